// Round 2
// baseline (590.818 us; speedup 1.0000x reference)
//
#include <hip/hip_runtime.h>
#include <hip/hip_bf16.h>

typedef unsigned short u16;
typedef __attribute__((ext_vector_type(8))) short short8;
typedef __attribute__((ext_vector_type(4))) float f32x4;
typedef __attribute__((ext_vector_type(4))) unsigned short u16x4;

#define NE 131072

// ws layout in u16 elements (bf16 transposed weights, [n][k] row-major)
#define OFF_WA 0        // 4 x [256][256]
#define OFF_WB 262144   // 4 x [128][256]
#define OFF_WF 393216   // 4 x [128][128]
#define OFF_WE 458752   // [128][32]
#define OFF_WS 462848   // [128]

__device__ __forceinline__ float b2f(u16 v) {
    unsigned int u = ((unsigned int)v) << 16;
    float f;
    __builtin_memcpy(&f, &u, 4);
    return f;
}
__device__ __forceinline__ u16 f2b(float f) {
    __hip_bfloat16 h = __float2bfloat16(f);
    u16 u;
    __builtin_memcpy(&u, &h, 2);
    return u;
}

#define MFMA16(a, b, c) __builtin_amdgcn_mfma_f32_16x16x32_bf16(a, b, c, 0, 0, 0)

struct BiasP {
    const float* ba[4];
    const float* bb[4];
};

__global__ void prep_kernel(const float* __restrict__ W1a, const float* __restrict__ W2a,
                            const float* __restrict__ W3a, const float* __restrict__ W4a,
                            const float* __restrict__ W1b, const float* __restrict__ W2b,
                            const float* __restrict__ W3b, const float* __restrict__ W4b,
                            const float* __restrict__ Wf,  u16* __restrict__ ws) {
    int y = blockIdx.y;
    int tid = blockIdx.x * 256 + threadIdx.x;
    if (y < 4) {
        if (tid < 65536) {
            const float* W = (y == 0) ? W1a : (y == 1) ? W2a : (y == 2) ? W3a : W4a;
            int n = tid >> 8, k = tid & 255;
            ws[OFF_WA + y * 65536 + tid] = f2b(W[k * 256 + n]);
        }
    } else if (y < 8) {
        if (tid < 32768) {
            const float* W = (y == 4) ? W1b : (y == 5) ? W2b : (y == 6) ? W3b : W4b;
            int n = tid >> 8, k = tid & 255;
            ws[OFF_WB + (y - 4) * 32768 + tid] = f2b(W[k * 128 + n]);
        }
    } else {
        if (tid < 69760) {           // 545 * 128
            int n = tid / 545;
            int k = tid - n * 545;
            u16 v = f2b(Wf[k * 128 + n]);
            if (k < 512)       ws[OFF_WF + (k >> 7) * 16384 + n * 128 + (k & 127)] = v;
            else if (k == 512) ws[OFF_WS + n] = v;
            else               ws[OFF_WE + n * 32 + (k - 513)] = v;
        }
    }
}

__global__ __launch_bounds__(256, 1)
void fused_kernel(const float* __restrict__ x, const int* __restrict__ ei,
                  const float* __restrict__ ea, const u16* __restrict__ ws,
                  BiasP bp, const float* __restrict__ bfp, float* __restrict__ out) {
    // 64 edges per block. Row pads: 264 (=256+8) / 136 / 40 -> 2-way bank aliasing only.
    __shared__ __align__(16) u16 Xs[64][264];
    __shared__ __align__(16) u16 Xd[64][264];
    __shared__ __align__(16) u16 Hs[64][264];
    __shared__ __align__(16) u16 Gs[64][136];
    __shared__ __align__(16) u16 EAs[64][40];
    __shared__ float scos[64];

    const int t = threadIdx.x;
    const int wave = t >> 6;
    const int lane = t & 63;
    const int l15 = lane & 15;
    const int g = lane >> 4;
    const int e0 = blockIdx.x * 64;

    const f32x4 zero4 = {0.f, 0.f, 0.f, 0.f};

    // Hedge: detect int64 edge_index (sampled high words all zero) vs int32.
    bool idx64 = true;
    #pragma unroll
    for (int i = 1; i < 16; i += 2) { idx64 = idx64 && (ei[i] == 0); }

    // ---- gather x rows (f32 -> bf16) + edge_attr tile into LDS ----
    {
        int rr = t >> 1;             // 0..127 : 64 src rows then 64 dst rows
        int h = t & 1;               // half of the 256-wide row
        int er = rr & 63;
        int pos = ((rr < 64) ? 0 : NE) + e0 + er;
        int idx = idx64 ? ei[2 * pos] : ei[pos];
        const float4* src = (const float4*)(x + (size_t)idx * 256 + h * 128);
        u16* dl = (rr < 64) ? &Xs[er][h * 128] : &Xd[er][h * 128];
        #pragma unroll
        for (int i = 0; i < 16; i++) {
            float4 a = src[2 * i];
            float4 b = src[2 * i + 1];
            short8 p;
            p[0] = (short)f2b(a.x); p[1] = (short)f2b(a.y);
            p[2] = (short)f2b(a.z); p[3] = (short)f2b(a.w);
            p[4] = (short)f2b(b.x); p[5] = (short)f2b(b.y);
            p[6] = (short)f2b(b.z); p[7] = (short)f2b(b.w);
            *(short8*)(dl + i * 8) = p;
        }
        int row = t >> 2, c = t & 3;
        const float4* sp = (const float4*)(ea + (size_t)(e0 + row) * 32 + c * 8);
        float4 a = sp[0];
        float4 b = sp[1];
        short8 p;
        p[0] = (short)f2b(a.x); p[1] = (short)f2b(a.y);
        p[2] = (short)f2b(a.z); p[3] = (short)f2b(a.w);
        p[4] = (short)f2b(b.x); p[5] = (short)f2b(b.y);
        p[6] = (short)f2b(b.z); p[7] = (short)f2b(b.w);
        *(short8*)(&EAs[row][c * 8]) = p;
    }
    __syncthreads();

    // ---- cosine similarity: 4 threads per edge, shuffle-reduce ----
    {
        int edge = t >> 2, q = t & 3;
        float dot = 0.f, ss = 0.f, dd = 0.f;
        #pragma unroll
        for (int i = 0; i < 16; i++) {
            int k = q * 64 + i * 4;
            u16x4 a = *(const u16x4*)&Xs[edge][k];
            u16x4 b = *(const u16x4*)&Xd[edge][k];
            #pragma unroll
            for (int j = 0; j < 4; j++) {
                float fa = b2f(a[j]);
                float fb = b2f(b[j]);
                dot += fa * fb;
                ss  += fa * fa;
                dd  += fb * fb;
            }
        }
        dot += __shfl_xor(dot, 1); ss += __shfl_xor(ss, 1); dd += __shfl_xor(dd, 1);
        dot += __shfl_xor(dot, 2); ss += __shfl_xor(ss, 2); dd += __shfl_xor(dd, 2);
        if (q == 0) {
            float ns = fmaxf(sqrtf(ss), 1e-8f);
            float nd = fmaxf(sqrtf(dd), 1e-8f);
            scos[edge] = dot / (ns * nd);
        }
    }

    f32x4 Facc[4][2];
    #pragma unroll
    for (int a = 0; a < 4; a++) {
        #pragma unroll
        for (int b = 0; b < 2; b++) { Facc[a][b] = zero4; }
    }

    const int colA = wave * 64;   // stage A: wave owns 64 of 256 cols
    const int colC = wave * 32;   // stage B/C: wave owns 32 of 128 cols

    #pragma unroll 1
    for (int m = 0; m < 4; m++) {
        // ===== stage A: H = relu(A @ Wa + ba); A in {Xs, Xd, Xs-Xd, Xs*Xd} =====
        f32x4 accA[4][4];
        #pragma unroll
        for (int a = 0; a < 4; a++) {
            #pragma unroll
            for (int b = 0; b < 4; b++) { accA[a][b] = zero4; }
        }
        const u16* wa = ws + OFF_WA + m * 65536;
        #pragma unroll
        for (int kk = 0; kk < 8; kk++) {
            const int k0 = kk * 32 + g * 8;
            short8 afr[4];
            short8 bfr[4];
            #pragma unroll
            for (int mt = 0; mt < 4; mt++) {
                const int rowi = mt * 16 + l15;
                if (m == 0) {
                    afr[mt] = *(const short8*)&Xs[rowi][k0];
                } else if (m == 1) {
                    afr[mt] = *(const short8*)&Xd[rowi][k0];
                } else {
                    short8 sa = *(const short8*)&Xs[rowi][k0];
                    short8 sd = *(const short8*)&Xd[rowi][k0];
                    short8 rr;
                    #pragma unroll
                    for (int j = 0; j < 8; j++) {
                        float fs = b2f((u16)sa[j]);
                        float fd = b2f((u16)sd[j]);
                        float v = (m == 2) ? (fs - fd) : (fs * fd);
                        rr[j] = (short)f2b(v);
                    }
                    afr[mt] = rr;
                }
            }
            #pragma unroll
            for (int nt = 0; nt < 4; nt++) {
                int col = colA + nt * 16 + l15;
                bfr[nt] = *(const short8*)(wa + col * 256 + k0);
            }
            #pragma unroll
            for (int mt = 0; mt < 4; mt++) {
                #pragma unroll
                for (int nt = 0; nt < 4; nt++) {
                    accA[mt][nt] = MFMA16(afr[mt], bfr[nt], accA[mt][nt]);
                }
            }
        }
        {
            const float* ba = bp.ba[m];
            #pragma unroll
            for (int nt = 0; nt < 4; nt++) {
                int col = colA + nt * 16 + l15;
                float bias = ba[col];
                #pragma unroll
                for (int mt = 0; mt < 4; mt++) {
                    #pragma unroll
                    for (int rg = 0; rg < 4; rg++) {
                        int row = mt * 16 + g * 4 + rg;
                        float v = fmaxf(accA[mt][nt][rg] + bias, 0.f);
                        Hs[row][col] = f2b(v);
                    }
                }
            }
        }
        __syncthreads();

        // ===== stage B: G = relu(H @ Wb + bb) =====
        f32x4 accB[4][2];
        #pragma unroll
        for (int a = 0; a < 4; a++) {
            #pragma unroll
            for (int b = 0; b < 2; b++) { accB[a][b] = zero4; }
        }
        const u16* wb = ws + OFF_WB + m * 32768;
        #pragma unroll
        for (int kk = 0; kk < 8; kk++) {
            const int k0 = kk * 32 + g * 8;
            short8 afr[4];
            short8 bfr[2];
            #pragma unroll
            for (int mt = 0; mt < 4; mt++) {
                afr[mt] = *(const short8*)&Hs[mt * 16 + l15][k0];
            }
            #pragma unroll
            for (int nt = 0; nt < 2; nt++) {
                int col = colC + nt * 16 + l15;
                bfr[nt] = *(const short8*)(wb + col * 256 + k0);
            }
            #pragma unroll
            for (int mt = 0; mt < 4; mt++) {
                #pragma unroll
                for (int nt = 0; nt < 2; nt++) {
                    accB[mt][nt] = MFMA16(afr[mt], bfr[nt], accB[mt][nt]);
                }
            }
        }
        {
            const float* bb = bp.bb[m];
            #pragma unroll
            for (int nt = 0; nt < 2; nt++) {
                int col = colC + nt * 16 + l15;
                float bias = bb[col];
                #pragma unroll
                for (int mt = 0; mt < 4; mt++) {
                    #pragma unroll
                    for (int rg = 0; rg < 4; rg++) {
                        int row = mt * 16 + g * 4 + rg;
                        float v = fmaxf(accB[mt][nt][rg] + bias, 0.f);
                        Gs[row][col] = f2b(v);
                    }
                }
            }
        }
        __syncthreads();

        // ===== stage C: Facc += G @ WfT_m =====
        const u16* wf = ws + OFF_WF + m * 16384;
        #pragma unroll
        for (int kk = 0; kk < 4; kk++) {
            const int k0 = kk * 32 + g * 8;
            short8 afr[4];
            short8 bfr[2];
            #pragma unroll
            for (int mt = 0; mt < 4; mt++) {
                afr[mt] = *(const short8*)&Gs[mt * 16 + l15][k0];
            }
            #pragma unroll
            for (int nt = 0; nt < 2; nt++) {
                int col = colC + nt * 16 + l15;
                bfr[nt] = *(const short8*)(wf + col * 128 + k0);
            }
            #pragma unroll
            for (int mt = 0; mt < 4; mt++) {
                #pragma unroll
                for (int nt = 0; nt < 2; nt++) {
                    Facc[mt][nt] = MFMA16(afr[mt], bfr[nt], Facc[mt][nt]);
                }
            }
        }
        __syncthreads();
    }

    // ===== edge_attr contribution: Facc += EA @ WeT (K=32, one iter) =====
    {
        const int k0 = g * 8;
        short8 afr[4];
        short8 bfr[2];
        #pragma unroll
        for (int mt = 0; mt < 4; mt++) {
            afr[mt] = *(const short8*)&EAs[mt * 16 + l15][k0];
        }
        #pragma unroll
        for (int nt = 0; nt < 2; nt++) {
            int col = colC + nt * 16 + l15;
            bfr[nt] = *(const short8*)(ws + OFF_WE + col * 32 + k0);
        }
        #pragma unroll
        for (int mt = 0; mt < 4; mt++) {
            #pragma unroll
            for (int nt = 0; nt < 2; nt++) {
                Facc[mt][nt] = MFMA16(afr[mt], bfr[nt], Facc[mt][nt]);
            }
        }
    }

    // ===== epilogue: + s*Wf[512] + bf, tanh, stage f32 in LDS, coalesced store =====
    float* os = (float*)&Xs[0][0];   // reuse Xs: 64 rows x 132 f32 = 33792 B (exact fit)
    #pragma unroll
    for (int nt = 0; nt < 2; nt++) {
        int col = colC + nt * 16 + l15;
        float bv  = bfp[col];
        float wsr = b2f(ws[OFF_WS + col]);
        #pragma unroll
        for (int mt = 0; mt < 4; mt++) {
            #pragma unroll
            for (int rg = 0; rg < 4; rg++) {
                int row = mt * 16 + g * 4 + rg;
                float v = Facc[mt][nt][rg] + scos[row] * wsr + bv;
                v = fminf(fmaxf(v, -15.f), 15.f);
                float e2 = __expf(2.f * v);
                float th = (e2 - 1.f) / (e2 + 1.f);
                os[row * 132 + col] = th;
            }
        }
    }
    __syncthreads();
    {
        int row = t >> 2, c = t & 3;
        float* op = out + (size_t)(e0 + row) * 128 + c * 32;
        const float* sp = os + row * 132 + c * 32;
        #pragma unroll
        for (int i = 0; i < 8; i++) {
            float4 v = *(const float4*)(sp + i * 4);
            *(float4*)(op + i * 4) = v;
        }
    }
}

extern "C" void kernel_launch(void* const* d_in, const int* in_sizes, int n_in,
                              void* d_out, int out_size, void* d_ws, size_t ws_size,
                              hipStream_t stream) {
    u16* ws = (u16*)d_ws;
    prep_kernel<<<dim3(273, 9), 256, 0, stream>>>(
        (const float*)d_in[3],  (const float*)d_in[7],  (const float*)d_in[11], (const float*)d_in[15],
        (const float*)d_in[5],  (const float*)d_in[9],  (const float*)d_in[13], (const float*)d_in[17],
        (const float*)d_in[19], ws);

    BiasP bp;
    bp.ba[0] = (const float*)d_in[4];  bp.ba[1] = (const float*)d_in[8];
    bp.ba[2] = (const float*)d_in[12]; bp.ba[3] = (const float*)d_in[16];
    bp.bb[0] = (const float*)d_in[6];  bp.bb[1] = (const float*)d_in[10];
    bp.bb[2] = (const float*)d_in[14]; bp.bb[3] = (const float*)d_in[18];

    fused_kernel<<<NE / 64, 256, 0, stream>>>(
        (const float*)d_in[0], (const int*)d_in[1], (const float*)d_in[2], ws,
        bp, (const float*)d_in[20], (float*)d_out);
}